// Round 1
// baseline (79.119 us; speedup 1.0000x reference)
//
#include <hip/hip_runtime.h>

// MaxUnpooling2D, up=(2,2).
// updates: [B=16, H=64, W=64, C=256] f32
// mask:    same shape, int32 flat index into out [B, 128, 128, 256]
// out:     [16, 128, 128, 256] f32
//
// Gather formulation: each thread handles one pooled cell x 4 channels.
// Mask construction guarantees each mask entry lands in its own 2x2 window
// at its own channel, so out[o] = (mask==o) ? updates : 0 over the 4 window
// candidates covers every output element exactly once -> no pre-zero,
// fully coalesced reads AND writes.

constexpr int B = 16, H = 64, W = 64, C = 256;
constexpr int W2 = 128;            // 2*W
constexpr int TOTAL4 = B * H * W * C / 4;   // 4,194,304 thread-units

__global__ __launch_bounds__(256) void
unpool_gather_kernel(const float4* __restrict__ upd,
                     const int4* __restrict__ msk,
                     float4* __restrict__ out)
{
    int i = blockIdx.x * blockDim.x + threadIdx.x;
    if (i >= TOTAL4) return;

    // i -> (spatial cell, channel-quad)
    int c  = (i & 63) << 2;        // channel base, C/4 = 64 quads
    int sp = i >> 6;               // hb*W + w, where hb = b*H + h
    int w  = sp & 63;              // W = 64
    int hb = sp >> 6;              // b*H + h

    // Output flat index of (b, 2h, 2w, c): b*H2+2h == 2*hb
    int o00 = 2 * (hb * W2 + w) * C + c;
    int o01 = o00 + C;             // (2h, 2w+1)
    int o10 = o00 + W2 * C;        // (2h+1, 2w)
    int o11 = o10 + C;             // (2h+1, 2w+1)

    int4   m = msk[i];
    float4 u = upd[i];

    float4 r00, r01, r10, r11;
    r00.x = (m.x == o00 + 0) ? u.x : 0.0f;
    r00.y = (m.y == o00 + 1) ? u.y : 0.0f;
    r00.z = (m.z == o00 + 2) ? u.z : 0.0f;
    r00.w = (m.w == o00 + 3) ? u.w : 0.0f;

    r01.x = (m.x == o01 + 0) ? u.x : 0.0f;
    r01.y = (m.y == o01 + 1) ? u.y : 0.0f;
    r01.z = (m.z == o01 + 2) ? u.z : 0.0f;
    r01.w = (m.w == o01 + 3) ? u.w : 0.0f;

    r10.x = (m.x == o10 + 0) ? u.x : 0.0f;
    r10.y = (m.y == o10 + 1) ? u.y : 0.0f;
    r10.z = (m.z == o10 + 2) ? u.z : 0.0f;
    r10.w = (m.w == o10 + 3) ? u.w : 0.0f;

    r11.x = (m.x == o11 + 0) ? u.x : 0.0f;
    r11.y = (m.y == o11 + 1) ? u.y : 0.0f;
    r11.z = (m.z == o11 + 2) ? u.z : 0.0f;
    r11.w = (m.w == o11 + 3) ? u.w : 0.0f;

    out[o00 >> 2] = r00;
    out[o01 >> 2] = r01;
    out[o10 >> 2] = r10;
    out[o11 >> 2] = r11;
}

extern "C" void kernel_launch(void* const* d_in, const int* in_sizes, int n_in,
                              void* d_out, int out_size, void* d_ws, size_t ws_size,
                              hipStream_t stream)
{
    const float4* upd = (const float4*)d_in[0];
    const int4*   msk = (const int4*)d_in[1];
    float4*       out = (float4*)d_out;

    constexpr int BLK = 256;
    constexpr int GRID = (TOTAL4 + BLK - 1) / BLK;   // 16384 blocks
    unpool_gather_kernel<<<GRID, BLK, 0, stream>>>(upd, msk, out);
}

// Round 3
// 74.417 us; speedup vs baseline: 1.0632x; 1.0632x over previous
//
#include <hip/hip_runtime.h>

// MaxUnpooling2D, up=(2,2).
// updates: [B=16, H=64, W=64, C=256] f32
// mask:    same shape, int32 flat index into out [B, 128, 128, 256]
// out:     [16, 128, 128, 256] f32
//
// Gather formulation: each thread handles one pooled cell x 4 channels.
// Mask construction guarantees each mask entry lands in its own 2x2 window
// at its own channel, so out[o] = (mask==o) ? updates : 0 over the 4 window
// candidates covers every output element exactly once -> no pre-zero,
// fully coalesced reads AND writes.
//
// R2: nontemporal builtins need native vector types, not HIP_vector_type
// (float4/int4 are classes) -> use ext_vector_type typedefs.

typedef float  f32x4 __attribute__((ext_vector_type(4)));
typedef int    i32x4 __attribute__((ext_vector_type(4)));

constexpr int B = 16, H = 64, W = 64, C = 256;
constexpr int W2 = 128;            // 2*W
constexpr int TOTAL4 = B * H * W * C / 4;   // 4,194,304 thread-units

__global__ __launch_bounds__(256) void
unpool_gather_kernel(const f32x4* __restrict__ upd,
                     const i32x4* __restrict__ msk,
                     f32x4* __restrict__ out)
{
    int i = blockIdx.x * blockDim.x + threadIdx.x;

    // i -> (spatial cell, channel-quad)
    int c  = (i & 63) << 2;        // channel base, C/4 = 64 quads
    int sp = i >> 6;               // hb*W + w, where hb = b*H + h
    int w  = sp & 63;              // W = 64
    int hb = sp >> 6;              // b*H + h

    // Output flat index of (b, 2h, 2w, c): b*H2+2h == 2*hb
    int o00 = 2 * (hb * W2 + w) * C + c;
    int o01 = o00 + C;             // (2h, 2w+1)
    int o10 = o00 + W2 * C;        // (2h+1, 2w)
    int o11 = o10 + C;             // (2h+1, 2w+1)

    i32x4 m = __builtin_nontemporal_load(msk + i);
    f32x4 u = __builtin_nontemporal_load(upd + i);

    f32x4 r00, r01, r10, r11;
    #pragma unroll
    for (int j = 0; j < 4; ++j) {
        r00[j] = (m[j] == o00 + j) ? u[j] : 0.0f;
        r01[j] = (m[j] == o01 + j) ? u[j] : 0.0f;
        r10[j] = (m[j] == o10 + j) ? u[j] : 0.0f;
        r11[j] = (m[j] == o11 + j) ? u[j] : 0.0f;
    }

    __builtin_nontemporal_store(r00, out + (o00 >> 2));
    __builtin_nontemporal_store(r01, out + (o01 >> 2));
    __builtin_nontemporal_store(r10, out + (o10 >> 2));
    __builtin_nontemporal_store(r11, out + (o11 >> 2));
}

extern "C" void kernel_launch(void* const* d_in, const int* in_sizes, int n_in,
                              void* d_out, int out_size, void* d_ws, size_t ws_size,
                              hipStream_t stream)
{
    const f32x4* upd = (const f32x4*)d_in[0];
    const i32x4* msk = (const i32x4*)d_in[1];
    f32x4*       out = (f32x4*)d_out;

    constexpr int BLK = 256;
    constexpr int GRID = TOTAL4 / BLK;   // 16384 blocks, exact
    unpool_gather_kernel<<<GRID, BLK, 0, stream>>>(upd, msk, out);
}